// Round 1
// baseline (62.710 us; speedup 1.0000x reference)
//
#include <hip/hip_runtime.h>
#include <hip/hip_bf16.h>

#define NB 32
#define NP 4096
#define NC 128
#define ND 128
#define TP 128            // points per block
#define EPSV 1e-16f

typedef __attribute__((ext_vector_type(8))) short short8;
typedef __attribute__((ext_vector_type(4))) float f32x4;

__device__ __forceinline__ unsigned short f2bf(float f) {
  __hip_bfloat16 h = __float2bfloat16(f);
  return *reinterpret_cast<unsigned short*>(&h);
}

// LDS byte-offset swizzle: row-major [row][128 bf16] with XOR of (row&7)<<4.
// Breaks the 16-way bank conflict on column-slice ds_read_b128 (G4 / T2).
__device__ __forceinline__ int swz(int row, int kbyte) {
  return (row * 256 + kbyte) ^ ((row & 7) << 4);
}

__global__ __launch_bounds__(256, 2) void cc_kernel(
    const int* __restrict__ indices,
    const float* __restrict__ qp,       // (B,P,3)
    const float* __restrict__ cpos,     // (R,C,3)
    const float* __restrict__ codes,    // (R,C,D)
    const void* __restrict__ dsp,       // dist_scale scalar
    float* __restrict__ out_qc,         // (B,P,D)
    float* __restrict__ out_sq,         // (B,P,C)
    float* __restrict__ out_wt) {       // (B,P,C)
  // wT: W matrix [row=point][k=code] bf16 swizzled (A operand, M x K)
  // cT: codes^T  [row=d]    [k=code] bf16 swizzled (B operand, N x K)
  __shared__ __align__(16) unsigned char wT[TP * NC * 2];
  __shared__ __align__(16) unsigned char cT[ND * NC * 2];

  const int tid = threadIdx.x;
  const int lane = tid & 63;
  const int wv = tid >> 6;
  const int b = blockIdx.x >> 5;
  const int p0 = (blockIdx.x & 31) * TP;
  const int rec = indices[b];

  // dist_scale: robust to int32 or float32 encoding
  const int si = ((const int*)dsp)[0];
  const float sv = (si > 0 && si < 1000) ? (float)si : ((const float*)dsp)[0];

  // ---- stage codes[rec] -> cT (transpose + bf16 + swizzle) ----
  const float* cb = codes + (size_t)rec * (NC * ND);
  #pragma unroll
  for (int it = 0; it < 16; ++it) {
    int i = tid * 4 + it * 1024;          // element index c*128 + d
    float4 v = *reinterpret_cast<const float4*>(cb + i);
    int c = i >> 7;
    int d0 = i & 127;
    float vv[4] = {v.x, v.y, v.z, v.w};
    #pragma unroll
    for (int j = 0; j < 4; ++j) {
      int d = d0 + j;
      *(unsigned short*)(cT + swz(d, c * 2)) = f2bf(vv[j]);
    }
  }

  // ---- positions for this lane's two codes: registers, loaded once ----
  const float* pp0 = cpos + ((size_t)rec * NC + lane) * 3;
  const float* pp1 = cpos + ((size_t)rec * NC + lane + 64) * 3;
  const float px0 = pp0[0], py0 = pp0[1], pz0 = pp0[2];
  const float px1 = pp1[0], py1 = pp1[1], pz1 = pp1[2];

  __syncthreads();

  // ---- phase 1: distances, weights, normalization; fill wT ----
  const size_t rowbase = (size_t)b * NP + p0;
  for (int pl = wv; pl < TP; pl += 4) {
    const float* q = qp + (rowbase + pl) * 3;
    const float qx = q[0], qy = q[1], qz = q[2];

    float dx = qx - px0, dy = qy - py0, dz = qz - pz0;
    const float d0 = fmaf(dx, dx, fmaf(dy, dy, dz * dz)) + EPSV;
    dx = qx - px1; dy = qy - py1; dz = qz - pz1;
    const float d1 = fmaf(dx, dx, fmaf(dy, dy, dz * dz)) + EPSV;

    float wu0, wu1;
    if (sv == 2.0f) {
      wu0 = 1.0f / d0;
      wu1 = 1.0f / d1;
    } else {
      wu0 = __powf(d0, -0.5f * sv);
      wu1 = __powf(d1, -0.5f * sv);
    }

    float s = wu0 + wu1;
    #pragma unroll
    for (int off = 32; off; off >>= 1) s += __shfl_xor(s, off, 64);
    const float inv = 1.0f / s;
    const float w0 = wu0 * inv, w1 = wu1 * inv;

    const size_t rb = (rowbase + pl) * NC;
    out_sq[rb + lane] = d0;
    out_sq[rb + lane + 64] = d1;
    out_wt[rb + lane] = w0;
    out_wt[rb + lane + 64] = w1;

    *(unsigned short*)(wT + swz(pl, lane * 2)) = f2bf(w0);
    *(unsigned short*)(wT + swz(pl, (lane + 64) * 2)) = f2bf(w1);
  }

  __syncthreads();

  // ---- phase 2: MFMA einsum. Wave wv owns output rows [wv*32, wv*32+32) ----
  const int m0 = wv * 32;
  const int l16 = lane & 15;
  const int kg = lane >> 4;            // 0..3 -> k block of 8
  f32x4 acc[2][8];
  #pragma unroll
  for (int mi = 0; mi < 2; ++mi)
    #pragma unroll
    for (int n = 0; n < 8; ++n)
      acc[mi][n] = (f32x4){0.f, 0.f, 0.f, 0.f};

  #pragma unroll
  for (int kk = 0; kk < NC; kk += 32) {
    const int kb = (kk + kg * 8) * 2;  // byte offset of this lane's k-slice
    const short8 a0 = *(const short8*)(wT + swz(m0 + l16, kb));
    const short8 a1 = *(const short8*)(wT + swz(m0 + 16 + l16, kb));
    #pragma unroll
    for (int n = 0; n < 8; ++n) {
      const short8 bb = *(const short8*)(cT + swz(n * 16 + l16, kb));
      acc[0][n] = __builtin_amdgcn_mfma_f32_16x16x32_bf16(a0, bb, acc[0][n], 0, 0, 0);
      acc[1][n] = __builtin_amdgcn_mfma_f32_16x16x32_bf16(a1, bb, acc[1][n], 0, 0, 0);
    }
  }

  // C/D layout (m89-verified): col = lane&15, row = (lane>>4)*4 + reg
  const int r4 = (lane >> 4) * 4;
  #pragma unroll
  for (int mi = 0; mi < 2; ++mi) {
    #pragma unroll
    for (int n = 0; n < 8; ++n) {
      #pragma unroll
      for (int j = 0; j < 4; ++j) {
        const int row = m0 + mi * 16 + r4 + j;
        const int col = n * 16 + l16;
        out_qc[(rowbase + row) * ND + col] = acc[mi][n][j];
      }
    }
  }
}

extern "C" void kernel_launch(void* const* d_in, const int* in_sizes, int n_in,
                              void* d_out, int out_size, void* d_ws, size_t ws_size,
                              hipStream_t stream) {
  const int* indices = (const int*)d_in[0];
  const float* qp = (const float*)d_in[1];
  const float* cpos = (const float*)d_in[2];
  const float* codes = (const float*)d_in[3];
  const void* dsp = d_in[4];

  float* out = (float*)d_out;
  float* qc = out;                                   // (B,P,D)
  float* sq = qc + (size_t)NB * NP * ND;             // (B,P,C)
  float* wt = sq + (size_t)NB * NP * NC;             // (B,P,C)

  dim3 grid(NB * (NP / TP));
  cc_kernel<<<grid, 256, 0, stream>>>(indices, qp, cpos, codes, dsp, qc, sq, wt);
}

// Round 2
// 44.703 us; speedup vs baseline: 1.4028x; 1.4028x over previous
//
#include <hip/hip_runtime.h>
#include <hip/hip_bf16.h>

#define NB 32
#define NP 4096
#define NC 128
#define ND 128
#define TP 128            // points per block
#define EPSV 1e-16f

typedef __attribute__((ext_vector_type(8))) short short8;
typedef __attribute__((ext_vector_type(4))) float f32x4;

__device__ __forceinline__ unsigned short f2bf(float f) {
  __hip_bfloat16 h = __float2bfloat16(f);
  return *reinterpret_cast<unsigned short*>(&h);
}

// LDS byte-offset swizzle: row-major [row][128 bf16] with XOR of (row&7)<<4.
__device__ __forceinline__ int swz(int row, int kbyte) {
  return (row * 256 + kbyte) ^ ((row & 7) << 4);
}

// Pre-kernel: build pre-swizzled bf16 "cT LDS images" (codes^T, [d][c]) for the
// 32 gathered records into d_ws. Deduplicates the f32->bf16 transpose that all
// 32 tiles of a batch would otherwise redo, and enables zero-VALU DMA staging
// in the main kernel (global_load_lds with pre-swizzled source, linear dest).
__global__ void cc_pre(const int* __restrict__ indices,
                       const float* __restrict__ codes,
                       unsigned char* __restrict__ ws) {
  const int b = blockIdx.x;
  const int rec = indices[b];
  const float* cb = codes + (size_t)rec * (NC * ND);
  unsigned char* wb = ws + (size_t)b * (NC * ND * 2);
  const int tid = threadIdx.x;        // 1024 threads
  const int d = tid & 127;
  const int cq0 = tid >> 7;           // 0..7
  #pragma unroll
  for (int it = 0; it < 4; ++it) {
    const int c = (cq0 + it * 8) * 4;
    unsigned long long v = 0;
    #pragma unroll
    for (int j = 0; j < 4; ++j)
      v |= (unsigned long long)f2bf(cb[(size_t)(c + j) * ND + d]) << (16 * j);
    // row d, cols c..c+3 -> 8 consecutive bytes (swizzle only flips bits 4-6)
    *(unsigned long long*)(wb + swz(d, c * 2)) = v;
  }
}

template<bool PRE>
__global__ __launch_bounds__(256, 2) void cc_main(
    const int* __restrict__ indices,
    const float* __restrict__ qp,       // (B,P,3)
    const float* __restrict__ cpos,     // (R,C,3)
    const float* __restrict__ codes,    // (R,C,D)
    const void* __restrict__ dsp,       // dist_scale scalar
    const unsigned char* __restrict__ wsc, // pre-swizzled bf16 cT images
    float* __restrict__ out_qc,         // (B,P,D)
    float* __restrict__ out_sq,         // (B,P,C)
    float* __restrict__ out_wt) {       // (B,P,C)
  __shared__ __align__(16) unsigned char wT[TP * NC * 2];   // W  [p][c] bf16 swz
  __shared__ __align__(16) unsigned char cT[ND * NC * 2];   // C^T[d][c] bf16 swz

  const int tid = threadIdx.x;
  const int lane = tid & 63;
  const int wv = tid >> 6;
  const int g = lane >> 4;            // 16-lane group -> point within quad
  const int l16 = lane & 15;
  const int c0 = l16 * 8;             // this lane's 8 codes
  const int b = blockIdx.x >> 5;
  const int p0 = (blockIdx.x & 31) * TP;
  const int rec = indices[b];

  const int si = ((const int*)dsp)[0];
  const float sv = (si > 0 && si < 1000) ? (float)si : ((const float*)dsp)[0];

  // ---- hoist all per-lane global reads into registers (independent, one latency)
  const float* pb = cpos + ((size_t)rec * NC + c0) * 3;
  float px[8], py[8], pz[8];
  #pragma unroll
  for (int j = 0; j < 8; ++j) {
    px[j] = pb[j * 3 + 0]; py[j] = pb[j * 3 + 1]; pz[j] = pb[j * 3 + 2];
  }

  const size_t rowbase = (size_t)b * NP + p0;
  float qx[8], qy[8], qz[8];
  #pragma unroll
  for (int it = 0; it < 8; ++it) {
    const int p = it * 16 + wv * 4 + g;
    const float* q = qp + (rowbase + p) * 3;
    qx[it] = q[0]; qy[it] = q[1]; qz[it] = q[2];
  }

  // ---- cT staging: issued AFTER the q/pos loads so their vmcnt waits don't
  // drain the DMA; the DMA completes under phase 1, drained at the barrier.
  if (PRE) {
    const unsigned char* src = wsc + (size_t)b * (NC * ND * 2);
    #pragma unroll
    for (int it = 0; it < 8; ++it) {
      const int off = (wv * 8 + it) * 1024;
      __builtin_amdgcn_global_load_lds(
          (const __attribute__((address_space(1))) void*)(src + off + lane * 16),
          (__attribute__((address_space(3))) void*)(cT + off),
          16, 0, 0);
    }
  } else {
    const float* cb = codes + (size_t)rec * (NC * ND);
    #pragma unroll
    for (int it = 0; it < 16; ++it) {
      int i = tid * 4 + it * 1024;
      float4 v = *reinterpret_cast<const float4*>(cb + i);
      int c = i >> 7, d0 = i & 127;
      float vv[4] = {v.x, v.y, v.z, v.w};
      #pragma unroll
      for (int j = 0; j < 4; ++j)
        *(unsigned short*)(cT + swz(d0 + j, c * 2)) = f2bf(vv[j]);
    }
  }

  // ---- phase 1: 4 points per wave in flight; lane owns 8 codes.
  const bool s2 = (sv == 2.0f);
  #pragma unroll
  for (int it = 0; it < 8; ++it) {
    const int p = it * 16 + wv * 4 + g;
    float dd[8], wu[8];
    #pragma unroll
    for (int j = 0; j < 8; ++j) {
      const float dx = qx[it] - px[j], dy = qy[it] - py[j], dz = qz[it] - pz[j];
      dd[j] = fmaf(dx, dx, fmaf(dy, dy, dz * dz)) + EPSV;
    }
    if (s2) {
      #pragma unroll
      for (int j = 0; j < 8; ++j) wu[j] = __builtin_amdgcn_rcpf(dd[j]);
    } else {
      #pragma unroll
      for (int j = 0; j < 8; ++j) wu[j] = __powf(dd[j], -0.5f * sv);
    }
    float s = ((wu[0] + wu[1]) + (wu[2] + wu[3])) + ((wu[4] + wu[5]) + (wu[6] + wu[7]));
    s += __shfl_xor(s, 1); s += __shfl_xor(s, 2);
    s += __shfl_xor(s, 4); s += __shfl_xor(s, 8);   // stays within 16-lane group
    const float inv = __builtin_amdgcn_rcpf(s);

    f32x4 dlo, dhi, wlo, whi;
    #pragma unroll
    for (int j = 0; j < 4; ++j) {
      dlo[j] = dd[j]; dhi[j] = dd[j + 4];
      wlo[j] = wu[j] * inv; whi[j] = wu[j + 4] * inv;
    }
    const size_t rb = (rowbase + p) * (size_t)NC + c0;
    *(f32x4*)(out_sq + rb) = dlo;
    *(f32x4*)(out_sq + rb + 4) = dhi;
    *(f32x4*)(out_wt + rb) = wlo;
    *(f32x4*)(out_wt + rb + 4) = whi;

    short8 w8;
    #pragma unroll
    for (int j = 0; j < 4; ++j) { w8[j] = (short)f2bf(wlo[j]); w8[j + 4] = (short)f2bf(whi[j]); }
    *(short8*)(wT + swz(p, c0 * 2)) = w8;           // one ds_write_b128
  }

  __syncthreads();   // drains wT writes + cT DMA (overlapped with phase 1)

  // ---- phase 2: MFMA einsum (validated round 1). Wave owns rows [wv*32, +32).
  const int m0 = wv * 32;
  const int kg = lane >> 4;
  f32x4 acc[2][8];
  #pragma unroll
  for (int mi = 0; mi < 2; ++mi)
    #pragma unroll
    for (int n = 0; n < 8; ++n)
      acc[mi][n] = (f32x4){0.f, 0.f, 0.f, 0.f};

  #pragma unroll
  for (int kk = 0; kk < NC; kk += 32) {
    const int kb = (kk + kg * 8) * 2;
    const short8 a0 = *(const short8*)(wT + swz(m0 + l16, kb));
    const short8 a1 = *(const short8*)(wT + swz(m0 + 16 + l16, kb));
    #pragma unroll
    for (int n = 0; n < 8; ++n) {
      const short8 bb = *(const short8*)(cT + swz(n * 16 + l16, kb));
      acc[0][n] = __builtin_amdgcn_mfma_f32_16x16x32_bf16(a0, bb, acc[0][n], 0, 0, 0);
      acc[1][n] = __builtin_amdgcn_mfma_f32_16x16x32_bf16(a1, bb, acc[1][n], 0, 0, 0);
    }
  }

  // C/D layout (m89-verified): col = lane&15, row = (lane>>4)*4 + reg
  const int r4 = (lane >> 4) * 4;
  #pragma unroll
  for (int mi = 0; mi < 2; ++mi) {
    #pragma unroll
    for (int n = 0; n < 8; ++n) {
      #pragma unroll
      for (int j = 0; j < 4; ++j) {
        const int row = m0 + mi * 16 + r4 + j;
        const int col = n * 16 + l16;
        out_qc[(rowbase + row) * ND + col] = acc[mi][n][j];
      }
    }
  }
}

extern "C" void kernel_launch(void* const* d_in, const int* in_sizes, int n_in,
                              void* d_out, int out_size, void* d_ws, size_t ws_size,
                              hipStream_t stream) {
  const int* indices = (const int*)d_in[0];
  const float* qp = (const float*)d_in[1];
  const float* cpos = (const float*)d_in[2];
  const float* codes = (const float*)d_in[3];
  const void* dsp = d_in[4];

  float* out = (float*)d_out;
  float* qc = out;                                   // (B,P,D)
  float* sq = qc + (size_t)NB * NP * ND;             // (B,P,C)
  float* wt = sq + (size_t)NB * NP * NC;             // (B,P,C)

  const size_t ws_need = (size_t)NB * NC * ND * 2;   // 1 MiB
  dim3 grid(NB * (NP / TP));
  if (ws_size >= ws_need) {
    cc_pre<<<dim3(NB), dim3(1024), 0, stream>>>(indices, codes, (unsigned char*)d_ws);
    cc_main<true><<<grid, 256, 0, stream>>>(indices, qp, cpos, codes, dsp,
                                            (const unsigned char*)d_ws, qc, sq, wt);
  } else {
    cc_main<false><<<grid, 256, 0, stream>>>(indices, qp, cpos, codes, dsp,
                                             nullptr, qc, sq, wt);
  }
}